// Round 6
// baseline (21955.804 us; speedup 1.0000x reference)
//
#include <hip/hip_runtime.h>

// RNNModel: B=64, T=512, I=256, H=1024, L=4 + FC(H->1).
// Round 6: layer-pipelined persistent kernel, 4x work per sync + de-contended
// polls.
//   - 4 pairs (= layers) x 16 wgs (64 features, ALL 64 batches) = 64 wgs,
//     1 wg/CU, 4 waves (1 wave/SIMD -> full VGPR budget).
//   - Per wave per step: 4 m-tiles x 4 n-tiles x (8 ih + 8 hh K-frags)
//     = 256 MFMAs; weights register-resident (256 VGPRs).
//   - Only wave 0 polls (64 pollers, was 1024 -> round-5 IC hot-lining);
//     flags spread 64 B apart; two-phase poll (producer/backpressure before
//     ih MFMAs, own-pair after) so ih compute hides sibling skew.
//   - All h/flag traffic RELAXED+SYSTEM bypass (IC-served, no buffer_inv /
//     wbl2 — round-3 lesson). Release = s_waitcnt vmcnt(0) + __syncthreads
//     before flag store (round-4/5 proven).
//   - FC fused into layer-3 wgs (atomicAdd fp32; out pre-init to fc_b).
// Workspace ~47 MB.

typedef _Float16 f16;
typedef _Float16 f16x8 __attribute__((ext_vector_type(8)));
typedef float    f32x4 __attribute__((ext_vector_type(4)));

#define BB 64
#define TT 512
#define II 256
#define HH 1024
#define RING 64

union U16u { unsigned long long u[2]; f16x8 v; };

#define SYS_LOAD_U64(p) __hip_atomic_load((const unsigned long long*)(p), \
    __ATOMIC_RELAXED, __HIP_MEMORY_SCOPE_SYSTEM)
#define SYS_STORE_U64(p, x) __hip_atomic_store((unsigned long long*)(p), (x), \
    __ATOMIC_RELAXED, __HIP_MEMORY_SCOPE_SYSTEM)

#define MFMA(a, b, c) __builtin_amdgcn_mfma_f32_16x16x32_f16((a), (b), (c), 0, 0, 0)

// ---------------- small prep kernels ----------------------------------------
__global__ __launch_bounds__(256) void cvt_kernel(const float* __restrict__ in,
                                                  f16* __restrict__ out, int n4) {
  int stride = gridDim.x * blockDim.x;
  for (int i = blockIdx.x * blockDim.x + threadIdx.x; i < n4; i += stride) {
    float4 v = reinterpret_cast<const float4*>(in)[i];
    _Float16 __attribute__((ext_vector_type(4))) h = { (f16)v.x, (f16)v.y,
                                                       (f16)v.z, (f16)v.w };
    reinterpret_cast<decltype(h)*>(out)[i] = h;
  }
}

__global__ __launch_bounds__(256) void bsum_kernel(const float* __restrict__ a,
                                                   const float* __restrict__ b,
                                                   float* __restrict__ o) {
  int i = blockIdx.x * blockDim.x + threadIdx.x;
  if (i < HH) o[i] = a[i] + b[i];
}

__global__ __launch_bounds__(256) void zero_kernel(int* __restrict__ p, int n) {
  int i = blockIdx.x * blockDim.x + threadIdx.x;
  if (i < n) p[i] = 0;
}

__global__ __launch_bounds__(256) void initout_kernel(float* __restrict__ out,
                                                      const float* __restrict__ fcb,
                                                      int n) {
  int i = blockIdx.x * blockDim.x + threadIdx.x;
  if (i < n) out[i] = fcb[0];
}

// ---------------- layer-pipelined persistent kernel --------------------------
// blockIdx: l = blk&3 (layer), wgp = blk>>2 (features [wgp*64, wgp*64+64)).
// wg covers ALL 64 batches (4 m-tiles). Wave w K-splits [w*256, w*256+256)
// and owns output n-tile w after the LDS reduce.
// flags[(l*16+wgp)*16] = #completed steps t (+1), SYSTEM-relaxed, 64B apart.
// Rings: ring_l[b][slot][feat], slot = t & 63.
// MFMA 16x16x32_f16: A lane=(m=l15, k=quad*8+j); B lane=(k=quad*8+j, n=l15)
// = 16B of W row n; C/D lane=(row=quad*4+i, col=l15).
__global__ __launch_bounds__(256, 1) void rnn_persist(
    const float* __restrict__ x,
    f16* __restrict__ ring0, f16* __restrict__ ring1,
    f16* __restrict__ ring2, f16* __restrict__ ring3,
    const f16* __restrict__ wih0, const f16* __restrict__ wih1,
    const f16* __restrict__ wih2, const f16* __restrict__ wih3,
    const f16* __restrict__ whh0, const f16* __restrict__ whh1,
    const f16* __restrict__ whh2, const f16* __restrict__ whh3,
    const float* __restrict__ bs0, const float* __restrict__ bs1,
    const float* __restrict__ bs2, const float* __restrict__ bs3,
    const float* __restrict__ fcw, float* __restrict__ out,
    int* __restrict__ flags) {
  const int l = blockIdx.x & 3;
  const int wgp = blockIdx.x >> 2;
  const int wave = threadIdx.x >> 6, lane = threadIdx.x & 63;
  const int l15 = lane & 15, quad = lane >> 4;
  const int r0 = wgp * 64;

  __shared__ f32x4 red[48 * 64];                 // 12 foreign tiles x 4 waves, 48 KB
  __shared__ __align__(16) f16 hstage[64 * 64];  // [batch][feature], 8 KB

  f16* rings[4] = { ring0, ring1, ring2, ring3 };
  const f16* wih_t[4] = { wih0, wih1, wih2, wih3 };
  const f16* whh_t[4] = { whh0, whh1, whh2, whh3 };
  const float* bs_t[4] = { bs0, bs1, bs2, bs3 };

  const f16* in_ring = (l > 0) ? rings[l - 1] : (const f16*)0;
  f16* out_ring = rings[l];
  const float bv = bs_t[l][r0 + wave * 16 + l15];

  // ---- register-resident weight fragments ----
  f16x8 whhF[4][8], wihF[4][8];
  {
    const f16* q = whh_t[l] + (size_t)(r0 + l15) * HH + wave * 256 + quad * 8;
#pragma unroll
    for (int n = 0; n < 4; ++n)
#pragma unroll
      for (int f = 0; f < 8; ++f)
        whhF[n][f] = *reinterpret_cast<const f16x8*>(q + (size_t)n * 16 * HH + f * 32);
  }
  if (l == 0) {
    const f16* q = wih0 + (size_t)(r0 + l15) * II + wave * 64 + quad * 8;
#pragma unroll
    for (int n = 0; n < 4; ++n)
#pragma unroll
      for (int f = 0; f < 2; ++f)
        wihF[n][f] = *reinterpret_cast<const f16x8*>(q + (size_t)n * 16 * II + f * 32);
  } else {
    const f16* q = wih_t[l] + (size_t)(r0 + l15) * HH + wave * 256 + quad * 8;
#pragma unroll
    for (int n = 0; n < 4; ++n)
#pragma unroll
      for (int f = 0; f < 8; ++f)
        wihF[n][f] = *reinterpret_cast<const f16x8*>(q + (size_t)n * 16 * HH + f * 32);
  }

  const int srow = threadIdx.x >> 2;  // 0..63 batch row for store/FC
  const int fg = threadIdx.x & 3;     // 16-feature group within wg
  float fcr[16];
  if (l == 3) {
#pragma unroll
    for (int j = 0; j < 16; ++j) fcr[j] = fcw[r0 + fg * 16 + j];
  }

  // ---- poll config (wave 0 only): which=0 own, 1 producer, 2 consumer ----
  const int which = lane >> 4;
  int psel = l + (which == 1 ? -1 : which == 2 ? 1 : 0);
  psel = psel < 0 ? 0 : (psel > 3 ? 3 : psel);
  const int* fptr = flags + (psel * 16 + l15) * 16;  // 64B-spread flags
  unsigned long long needA = 0;
  if (l > 0) needA |= 0xFFFF0000ull;
  if (l < 3) needA |= 0xFFFF00000000ull;
  int* myflag = flags + (l * 16 + wgp) * 16;

  for (int t = 0; t < TT; ++t) {
    const int slot = t & (RING - 1);

    // ---- phase A: producer has in[t] (>= t+1); consumer freed slot ----
    if (wave == 0 && needA && (l > 0 || t >= RING)) {
      const int tgtA = (which == 1) ? t + 1 : t - RING + 1;
      const bool part = (which == 1 && l > 0) || (which == 2 && l < 3);
      for (;;) {
        int v = part ? __hip_atomic_load(fptr, __ATOMIC_RELAXED,
                                         __HIP_MEMORY_SCOPE_SYSTEM)
                     : 0x7FFFFFFF;
        if ((__ballot(v >= tgtA) & needA) == needA) break;
      }
    }
    __syncthreads();

    f32x4 c[4][4];
#pragma unroll
    for (int m = 0; m < 4; ++m)
#pragma unroll
      for (int n = 0; n < 4; ++n) c[m][n] = f32x4{ 0.f, 0.f, 0.f, 0.f };

    // ---- ih MFMAs (hides own-pair flag skew) ----
    if (l == 0) {
#pragma unroll
      for (int m = 0; m < 4; ++m) {
        const float* xp = x + ((size_t)(m * 16 + l15) * TT + t) * II + wave * 64 + quad * 8;
#pragma unroll
        for (int f = 0; f < 2; ++f) {
          float4 u0 = *reinterpret_cast<const float4*>(xp + f * 32);
          float4 u1 = *reinterpret_cast<const float4*>(xp + f * 32 + 4);
          f16x8 a = { (f16)u0.x, (f16)u0.y, (f16)u0.z, (f16)u0.w,
                      (f16)u1.x, (f16)u1.y, (f16)u1.z, (f16)u1.w };
#pragma unroll
          for (int n = 0; n < 4; ++n) c[m][n] = MFMA(a, wihF[n][f], c[m][n]);
        }
      }
    } else {
#pragma unroll
      for (int f = 0; f < 8; ++f)
#pragma unroll
        for (int m = 0; m < 4; ++m) {
          const char* ip = (const char*)(in_ring +
              ((size_t)(m * 16 + l15) * RING + slot) * HH + wave * 256 + quad * 8 + f * 32);
          U16u av;
          av.u[0] = SYS_LOAD_U64(ip);
          av.u[1] = SYS_LOAD_U64(ip + 8);
#pragma unroll
          for (int n = 0; n < 4; ++n) c[m][n] = MFMA(av.v, wihF[n][f], c[m][n]);
        }
    }

    // ---- phase B: own pair finished step t-1 ----
    if (wave == 0 && t > 0) {
      for (;;) {
        int v = (which == 0) ? __hip_atomic_load(fptr, __ATOMIC_RELAXED,
                                                 __HIP_MEMORY_SCOPE_SYSTEM)
                             : 0x7FFFFFFF;
        if ((__ballot(v >= t) & 0xFFFFull) == 0xFFFFull) break;
      }
    }
    __syncthreads();

    // ---- hh MFMAs ----
    if (t > 0) {
      const int slotp = (t - 1) & (RING - 1);
#pragma unroll
      for (int f = 0; f < 8; ++f)
#pragma unroll
        for (int m = 0; m < 4; ++m) {
          const char* hp = (const char*)(out_ring +
              ((size_t)(m * 16 + l15) * RING + slotp) * HH + wave * 256 + quad * 8 + f * 32);
          U16u av;
          av.u[0] = SYS_LOAD_U64(hp);
          av.u[1] = SYS_LOAD_U64(hp + 8);
#pragma unroll
          for (int n = 0; n < 4; ++n) c[m][n] = MFMA(av.v, whhF[n][f], c[m][n]);
        }
    }

    // ---- cross-wave K-reduce: write 12 foreign tiles, keep own 4 ----
#pragma unroll
    for (int n = 0; n < 4; ++n) {
      if (n == wave) continue;  // wave-uniform branch
      const int nidx = (n < wave) ? n : n - 1;
#pragma unroll
      for (int m = 0; m < 4; ++m)
        red[((wave * 3 + nidx) * 4 + m) * 64 + lane] = c[m][n];
    }
    __syncthreads();
    f32x4 tot[4];
#pragma unroll
    for (int m = 0; m < 4; ++m) tot[m] = c[m][wave];
#pragma unroll
    for (int src = 0; src < 4; ++src) {
      if (src == wave) continue;
      const int nidx = (wave < src) ? wave : wave - 1;
#pragma unroll
      for (int m = 0; m < 4; ++m)
        tot[m] += red[((src * 3 + nidx) * 4 + m) * 64 + lane];
    }

    // ---- bias + tanh -> [batch][feature] stage ----
#pragma unroll
    for (int m = 0; m < 4; ++m)
#pragma unroll
      for (int i = 0; i < 4; ++i) {
        float e = __expf(2.0f * (tot[m][i] + bv));  // tanh = 1 - 2/(e^{2x}+1)
        hstage[(m * 16 + quad * 4 + i) * 64 + wave * 16 + l15] =
            (f16)(1.0f - 2.0f / (e + 1.0f));
      }
    __syncthreads();

    // ---- 32B (4x u64) bypass store per thread + fused FC ----
    {
      const f16* hrow = &hstage[srow * 64 + fg * 16];
      f16* dst = out_ring + ((size_t)srow * RING + slot) * HH + r0 + fg * 16;
      const unsigned long long* hu = reinterpret_cast<const unsigned long long*>(hrow);
#pragma unroll
      for (int k = 0; k < 4; ++k) SYS_STORE_U64(dst + k * 4, hu[k]);
      if (l == 3) {
        float partial = 0.f;
#pragma unroll
        for (int j = 0; j < 16; ++j) partial += (float)hrow[j] * fcr[j];
        partial += __shfl_down(partial, 1, 4);
        partial += __shfl_down(partial, 2, 4);
        if (fg == 0) atomicAdd(out + (size_t)srow * TT + t, partial);
      }
    }
    asm volatile("s_waitcnt vmcnt(0)" ::: "memory");  // stores acked at IC
    __syncthreads();                                  // all waves done
    if (threadIdx.x == 0)
      __hip_atomic_store(myflag, t + 1, __ATOMIC_RELAXED, __HIP_MEMORY_SCOPE_SYSTEM);
  }
}

extern "C" void kernel_launch(void* const* d_in, const int* in_sizes, int n_in,
                              void* d_out, int out_size, void* d_ws, size_t ws_size,
                              hipStream_t stream) {
  const float* x   = (const float*)d_in[0];
  const float* fcw = (const float*)d_in[17];
  const float* fcb = (const float*)d_in[18];

  char* ws = (char*)d_ws;
  size_t off = 0;
  auto alloc = [&](size_t bytes) -> void* {
    void* p = ws + off;
    off += (bytes + 255) & ~(size_t)255;
    return p;
  };
  f16* ring[4];
  for (int l = 0; l < 4; ++l)
    ring[l] = (f16*)alloc((size_t)BB * RING * HH * 2);  // 8 MB each
  f16* w16ih[4];
  f16* w16hh[4];
  float* bsum[4];
  for (int l = 0; l < 4; ++l) {
    int din = (l == 0) ? II : HH;
    w16ih[l] = (f16*)alloc((size_t)HH * din * 2);
    w16hh[l] = (f16*)alloc((size_t)HH * HH * 2);
    bsum[l]  = (float*)alloc(HH * 4);
  }
  int* flags = (int*)alloc(4 * 16 * 16 * 4);  // 64 flags, 64B apart; total ~47 MB

  for (int l = 0; l < 4; ++l) {
    int din = (l == 0) ? II : HH;
    cvt_kernel<<<512, 256, 0, stream>>>((const float*)d_in[1 + 4 * l], w16ih[l],
                                        HH * din / 4);
    cvt_kernel<<<512, 256, 0, stream>>>((const float*)d_in[2 + 4 * l], w16hh[l],
                                        HH * HH / 4);
    bsum_kernel<<<4, 256, 0, stream>>>((const float*)d_in[3 + 4 * l],
                                       (const float*)d_in[4 + 4 * l], bsum[l]);
  }
  zero_kernel<<<4, 256, 0, stream>>>(flags, 4 * 16 * 16);
  initout_kernel<<<BB * TT / 256, 256, 0, stream>>>((float*)d_out, fcb, BB * TT);

  rnn_persist<<<64, 256, 0, stream>>>(
      x, ring[0], ring[1], ring[2], ring[3],
      w16ih[0], w16ih[1], w16ih[2], w16ih[3],
      w16hh[0], w16hh[1], w16hh[2], w16hh[3],
      bsum[0], bsum[1], bsum[2], bsum[3],
      fcw, (float*)d_out, flags);
}

// Round 7
// 3320.638 us; speedup vs baseline: 6.6119x; 6.6119x over previous
//
#include <hip/hip_runtime.h>

// RNNModel: B=64, T=512, I=256, H=1024, L=4 + FC(H->1).
// Round 7: round-5 structure (3.29 ms proven) + ONLY poll de-contention.
//   Round-6 lesson: 4x batch merge hit the 512-reg ceiling (VGPR 232+AGPR,
//   spill + no free regs to keep bypass loads in flight) -> 6.7x regression.
//   Reverted. Isolated changes vs round 5:
//     1. wave-0-only polling (64 pollers, was 1024).
//     2. flags spread to one 64B line each.
//     3. two-phase poll: producer/backpressure BEFORE ih work, own-pair
//        AFTER (ih MFMAs hide producer skew). +2 syncthreads/step.
//   - 16 pairs (layer l, batch-group bg) x 16 wgs (64 features) = 256 wgs,
//     1 wg/CU, 4 waves/wg; W_ih/W_hh register-resident (256 VGPRs).
//   - Ring buffers RING=64 + flag sync; phi(l,t)=4t+l decreases along all
//     deps -> deadlock-free. All h/flag traffic RELAXED+SYSTEM bypass
//     (IC-served, no buffer_inv/wbl2). Release = s_waitcnt vmcnt(0) +
//     __syncthreads + flag store (round-4/5 proven).
//   - FC fused into layer-3 wgs (atomicAdd fp32; out pre-init to fc_b).
// Workspace ~47 MB.

typedef _Float16 f16;
typedef _Float16 f16x8 __attribute__((ext_vector_type(8)));
typedef float    f32x4 __attribute__((ext_vector_type(4)));

#define BB 64
#define TT 512
#define II 256
#define HH 1024
#define RING 64

union U16u { unsigned long long u[2]; f16x8 v; };

#define SYS_LOAD_U64(p) __hip_atomic_load((const unsigned long long*)(p), \
    __ATOMIC_RELAXED, __HIP_MEMORY_SCOPE_SYSTEM)
#define SYS_STORE_U64(p, x) __hip_atomic_store((unsigned long long*)(p), (x), \
    __ATOMIC_RELAXED, __HIP_MEMORY_SCOPE_SYSTEM)

#define MFMA(a, b, c) __builtin_amdgcn_mfma_f32_16x16x32_f16((a), (b), (c), 0, 0, 0)

// ---------------- small prep kernels ----------------------------------------
__global__ __launch_bounds__(256) void cvt_kernel(const float* __restrict__ in,
                                                  f16* __restrict__ out, int n4) {
  int stride = gridDim.x * blockDim.x;
  for (int i = blockIdx.x * blockDim.x + threadIdx.x; i < n4; i += stride) {
    float4 v = reinterpret_cast<const float4*>(in)[i];
    _Float16 __attribute__((ext_vector_type(4))) h = { (f16)v.x, (f16)v.y,
                                                       (f16)v.z, (f16)v.w };
    reinterpret_cast<decltype(h)*>(out)[i] = h;
  }
}

__global__ __launch_bounds__(256) void bsum_kernel(const float* __restrict__ a,
                                                   const float* __restrict__ b,
                                                   float* __restrict__ o) {
  int i = blockIdx.x * blockDim.x + threadIdx.x;
  if (i < HH) o[i] = a[i] + b[i];
}

__global__ __launch_bounds__(256) void zero_kernel(int* __restrict__ p, int n) {
  int i = blockIdx.x * blockDim.x + threadIdx.x;
  if (i < n) p[i] = 0;
}

__global__ __launch_bounds__(256) void initout_kernel(float* __restrict__ out,
                                                      const float* __restrict__ fcb,
                                                      int n) {
  int i = blockIdx.x * blockDim.x + threadIdx.x;
  if (i < n) out[i] = fcb[0];
}

// ---------------- layer-pipelined persistent kernel --------------------------
// blockIdx: p = blk&15 (pair: l=p>>2, bg=p&3), wgp = blk>>4 (features
// [wgp*64, wgp*64+64)). Wave w K-splits [w*256, w*256+256) and owns output
// n-tile w (cols wgp*64 + w*16..+16) after the LDS reduce.
// flags[(p*16+wgp)*16] = #completed steps t (+1) of pair p's wg wgp (64B
// apart). Rings: ring_l[b][slot][feat], slot = t & 63.
// MFMA 16x16x32_f16: A lane=(m=l15, k=quad*8+j); B lane=(k=quad*8+j, n=l15)
// = 16B of W row n; C/D lane=(row=quad*4+i, col=l15).
__global__ __launch_bounds__(256, 1) void rnn_persist(
    const float* __restrict__ x,
    f16* __restrict__ ring0, f16* __restrict__ ring1,
    f16* __restrict__ ring2, f16* __restrict__ ring3,
    const f16* __restrict__ wih0, const f16* __restrict__ wih1,
    const f16* __restrict__ wih2, const f16* __restrict__ wih3,
    const f16* __restrict__ whh0, const f16* __restrict__ whh1,
    const f16* __restrict__ whh2, const f16* __restrict__ whh3,
    const float* __restrict__ bs0, const float* __restrict__ bs1,
    const float* __restrict__ bs2, const float* __restrict__ bs3,
    const float* __restrict__ fcw, float* __restrict__ out,
    int* __restrict__ flags) {
  const int p = blockIdx.x & 15, wgp = blockIdx.x >> 4;
  const int l = p >> 2, bg = p & 3;
  const int wave = threadIdx.x >> 6, lane = threadIdx.x & 63;
  const int l15 = lane & 15, quad = lane >> 4;
  const int b0 = bg * 16, r0 = wgp * 64;
  const int srow = threadIdx.x >> 4;        // batch row for h store
  const int scol = (threadIdx.x & 15) * 4;  // feature col group

  __shared__ f32x4 red[16 * 64];                 // 16 KB
  __shared__ __align__(16) f16 hstage[16 * 64];  // 2 KB

  f16* rings[4] = { ring0, ring1, ring2, ring3 };
  const f16* wih_t[4] = { wih0, wih1, wih2, wih3 };
  const f16* whh_t[4] = { whh0, whh1, whh2, whh3 };
  const float* bs_t[4] = { bs0, bs1, bs2, bs3 };

  const f16* in_ring = (l > 0) ? rings[l - 1] : (const f16*)0;
  f16* out_ring = rings[l];
  const float bv = bs_t[l][r0 + wave * 16 + l15];

  // ---- register-resident weight fragments (1 wave/SIMD -> full budget) ----
  f16x8 whhF[4][8];
  {
    const f16* q = whh_t[l] + (size_t)(r0 + l15) * HH + wave * 256 + quad * 8;
#pragma unroll
    for (int j = 0; j < 4; ++j)
#pragma unroll
      for (int f = 0; f < 8; ++f)
        whhF[j][f] = *reinterpret_cast<const f16x8*>(q + (size_t)j * 16 * HH + f * 32);
  }
  f16x8 wihF[4][8];
  if (l == 0) {
    const f16* q = wih0 + (size_t)(r0 + l15) * II + wave * 64 + quad * 8;
#pragma unroll
    for (int j = 0; j < 4; ++j)
#pragma unroll
      for (int f = 0; f < 2; ++f)
        wihF[j][f] = *reinterpret_cast<const f16x8*>(q + (size_t)j * 16 * II + f * 32);
  } else {
    const f16* q = wih_t[l] + (size_t)(r0 + l15) * HH + wave * 256 + quad * 8;
#pragma unroll
    for (int j = 0; j < 4; ++j)
#pragma unroll
      for (int f = 0; f < 8; ++f)
        wihF[j][f] = *reinterpret_cast<const f16x8*>(q + (size_t)j * 16 * HH + f * 32);
  }
  float4 fcwv = { 0.f, 0.f, 0.f, 0.f };
  if (l == 3) fcwv = *reinterpret_cast<const float4*>(fcw + r0 + (threadIdx.x & 15) * 4);

  // ---- poll config (wave 0 only): which=0 own, 1 producer, 2 consumer ----
  const int which = lane >> 4;
  int psel = p + (which == 1 ? -4 : which == 2 ? 4 : 0);
  psel = psel < 0 ? 0 : (psel > 15 ? 15 : psel);
  const int* fptr = flags + (psel * 16 + l15) * 16;  // 64B-spread flags
  unsigned long long needA = 0;
  if (l > 0) needA |= 0xFFFF0000ull;
  if (l < 3) needA |= 0xFFFF00000000ull;
  int* myflag = flags + (p * 16 + wgp) * 16;

  for (int t = 0; t < TT; ++t) {
    const int slot = t & (RING - 1);
    f32x4 c0 = {}, c1 = {}, c2 = {}, c3 = {};

    // ---- phase A (wave 0): producer has in[t]; consumer freed ring slot ----
    if (wave == 0 && needA && (l > 0 || t >= RING)) {
      const int tgtA = (which == 1) ? t + 1 : t - RING + 1;
      const bool part = (which == 1 && l > 0) || (which == 2 && l < 3);
      for (;;) {
        int v = part ? __hip_atomic_load(fptr, __ATOMIC_RELAXED,
                                         __HIP_MEMORY_SCOPE_SYSTEM)
                     : 0x7FFFFFFF;
        if ((__ballot(v >= tgtA) & needA) == needA) break;
      }
    }
    if (l > 0) __syncthreads();  // gate ih ring loads on phase A

    // ---- ih MFMAs ----
    if (l == 0) {
      const float* xp = x + ((size_t)(b0 + l15) * TT + t) * II + wave * 64 + quad * 8;
#pragma unroll
      for (int f = 0; f < 2; ++f) {
        float4 u0 = *reinterpret_cast<const float4*>(xp + f * 32);
        float4 u1 = *reinterpret_cast<const float4*>(xp + f * 32 + 4);
        f16x8 a = { (f16)u0.x, (f16)u0.y, (f16)u0.z, (f16)u0.w,
                    (f16)u1.x, (f16)u1.y, (f16)u1.z, (f16)u1.w };
        c0 = MFMA(a, wihF[0][f], c0);
        c1 = MFMA(a, wihF[1][f], c1);
        c2 = MFMA(a, wihF[2][f], c2);
        c3 = MFMA(a, wihF[3][f], c3);
      }
    } else {
      const char* ip = (const char*)(in_ring + ((size_t)(b0 + l15) * RING + slot) * HH +
                                     wave * 256 + quad * 8);
#pragma unroll
      for (int f = 0; f < 8; ++f) {
        U16u av;
        av.u[0] = SYS_LOAD_U64(ip + f * 64);
        av.u[1] = SYS_LOAD_U64(ip + f * 64 + 8);
        c0 = MFMA(av.v, wihF[0][f], c0);
        c1 = MFMA(av.v, wihF[1][f], c1);
        c2 = MFMA(av.v, wihF[2][f], c2);
        c3 = MFMA(av.v, wihF[3][f], c3);
      }
    }

    // ---- phase B (wave 0): own pair finished step t-1 ----
    if (t > 0) {
      if (wave == 0) {
        for (;;) {
          int v = (which == 0) ? __hip_atomic_load(fptr, __ATOMIC_RELAXED,
                                                   __HIP_MEMORY_SCOPE_SYSTEM)
                               : 0x7FFFFFFF;
          if ((__ballot(v >= t) & 0xFFFFull) == 0xFFFFull) break;
        }
      }
      __syncthreads();  // gate hh ring loads on phase B

      const int slotp = (t - 1) & (RING - 1);
      const char* hp = (const char*)(out_ring + ((size_t)(b0 + l15) * RING + slotp) * HH +
                                     wave * 256 + quad * 8);
#pragma unroll
      for (int f = 0; f < 8; ++f) {
        U16u av;
        av.u[0] = SYS_LOAD_U64(hp + f * 64);
        av.u[1] = SYS_LOAD_U64(hp + f * 64 + 8);
        c0 = MFMA(av.v, whhF[0][f], c0);
        c1 = MFMA(av.v, whhF[1][f], c1);
        c2 = MFMA(av.v, whhF[2][f], c2);
        c3 = MFMA(av.v, whhF[3][f], c3);
      }
    }

    // ---- cross-wave K-reduce: wave w takes n-tile w ----
    red[(wave * 4 + 0) * 64 + lane] = c0;
    red[(wave * 4 + 1) * 64 + lane] = c1;
    red[(wave * 4 + 2) * 64 + lane] = c2;
    red[(wave * 4 + 3) * 64 + lane] = c3;
    __syncthreads();
    f32x4 tot = red[(0 * 4 + wave) * 64 + lane] + red[(1 * 4 + wave) * 64 + lane] +
                red[(2 * 4 + wave) * 64 + lane] + red[(3 * 4 + wave) * 64 + lane];

    // ---- bias + tanh, repack to [batch][feature] ----
#pragma unroll
    for (int i = 0; i < 4; ++i) {
      float e = __expf(2.0f * (tot[i] + bv));   // tanh(x) = 1 - 2/(e^{2x}+1)
      hstage[(quad * 4 + i) * 64 + wave * 16 + l15] = (f16)(1.0f - 2.0f / (e + 1.0f));
    }
    __syncthreads();

    // ---- one aligned 8B bypass store per thread into own ring slot ----
    unsigned long long hw =
        *reinterpret_cast<const unsigned long long*>(&hstage[srow * 64 + scol]);
    SYS_STORE_U64(out_ring + ((size_t)(b0 + srow) * RING + slot) * HH + r0 + scol, hw);

    // ---- fused FC for layer 3 ----
    if (l == 3) {
      union { unsigned long long u; f16 h[4]; } hu;
      hu.u = hw;
      float partial = (float)hu.h[0] * fcwv.x + (float)hu.h[1] * fcwv.y +
                      (float)hu.h[2] * fcwv.z + (float)hu.h[3] * fcwv.w;
      partial += __shfl_down(partial, 8, 16);
      partial += __shfl_down(partial, 4, 16);
      partial += __shfl_down(partial, 2, 16);
      partial += __shfl_down(partial, 1, 16);
      if ((threadIdx.x & 15) == 0)
        atomicAdd(out + (size_t)(b0 + srow) * TT + t, partial);
    }

    asm volatile("s_waitcnt vmcnt(0)" ::: "memory");  // stores acked at IC
    __syncthreads();                                  // all waves done
    if (threadIdx.x == 0)
      __hip_atomic_store(myflag, t + 1, __ATOMIC_RELAXED, __HIP_MEMORY_SCOPE_SYSTEM);
  }
}

extern "C" void kernel_launch(void* const* d_in, const int* in_sizes, int n_in,
                              void* d_out, int out_size, void* d_ws, size_t ws_size,
                              hipStream_t stream) {
  const float* x   = (const float*)d_in[0];
  const float* fcw = (const float*)d_in[17];
  const float* fcb = (const float*)d_in[18];

  char* ws = (char*)d_ws;
  size_t off = 0;
  auto alloc = [&](size_t bytes) -> void* {
    void* p = ws + off;
    off += (bytes + 255) & ~(size_t)255;
    return p;
  };
  f16* ring[4];
  for (int l = 0; l < 4; ++l)
    ring[l] = (f16*)alloc((size_t)BB * RING * HH * 2);  // 8 MB each
  f16* w16ih[4];
  f16* w16hh[4];
  float* bsum[4];
  for (int l = 0; l < 4; ++l) {
    int din = (l == 0) ? II : HH;
    w16ih[l] = (f16*)alloc((size_t)HH * din * 2);
    w16hh[l] = (f16*)alloc((size_t)HH * HH * 2);
    bsum[l]  = (float*)alloc(HH * 4);
  }
  int* flags = (int*)alloc(256 * 16 * 4);  // 256 flags, 64B apart; total ~47 MB

  for (int l = 0; l < 4; ++l) {
    int din = (l == 0) ? II : HH;
    cvt_kernel<<<512, 256, 0, stream>>>((const float*)d_in[1 + 4 * l], w16ih[l],
                                        HH * din / 4);
    cvt_kernel<<<512, 256, 0, stream>>>((const float*)d_in[2 + 4 * l], w16hh[l],
                                        HH * HH / 4);
    bsum_kernel<<<4, 256, 0, stream>>>((const float*)d_in[3 + 4 * l],
                                       (const float*)d_in[4 + 4 * l], bsum[l]);
  }
  zero_kernel<<<16, 256, 0, stream>>>(flags, 256 * 16);
  initout_kernel<<<BB * TT / 256, 256, 0, stream>>>((float*)d_out, fcb, BB * TT);

  rnn_persist<<<256, 256, 0, stream>>>(
      x, ring[0], ring[1], ring[2], ring[3],
      w16ih[0], w16ih[1], w16ih[2], w16ih[3],
      w16hh[0], w16hh[1], w16hh[2], w16hh[3],
      bsum[0], bsum[1], bsum[2], bsum[3],
      fcw, (float*)d_out, flags);
}

// Round 10
// 3042.974 us; speedup vs baseline: 7.2152x; 1.0912x over previous
//
#include <hip/hip_runtime.h>

// RNNModel: B=64, T=512, I=256, H=1024, L=4 + FC(H->1).
// Round 10: round 9 + THE fix: hfast was indexed by bg ONLY -- all 4 layers
//   with the same batch-group aliased one 2-slot ping-pong (layers overwrote
//   each other's h => absmax 0.3 in rounds 8 AND 9). Now per-pair:
//   hfast = hfastg + p * 2*16*HH (1 MB total). Round-9 release-barrier fix
//   retained (waitcnt -> __syncthreads -> tid0 publish).
//   Structure: pair p=(layer,bg) on blockIdx%16 -> 16 wgs share blockIdx%8 ->
//   same XCD (runtime census via HW_REG_XCC_ID; fallback = system path).
//   Intra-pair h/flag via sc0 (XCD-L2). Cross-pair ring/flag_sys system-scope
//   (IC), publish deferred one step, hidden behind ih MFMAs.

typedef _Float16 f16;
typedef _Float16 f16x8 __attribute__((ext_vector_type(8)));
typedef float    f32x4 __attribute__((ext_vector_type(4)));

#define BB 64
#define TT 512
#define II 256
#define HH 1024
#define RING 64

union U16u { unsigned long long u[2]; f16x8 v; };

#define SYS_LOAD_U64(p) __hip_atomic_load((const unsigned long long*)(p), \
    __ATOMIC_RELAXED, __HIP_MEMORY_SCOPE_SYSTEM)
#define SYS_STORE_U64(p, x) __hip_atomic_store((unsigned long long*)(p), (x), \
    __ATOMIC_RELAXED, __HIP_MEMORY_SCOPE_SYSTEM)
#define SYS_LOAD_I32(p) __hip_atomic_load((const int*)(p), \
    __ATOMIC_RELAXED, __HIP_MEMORY_SCOPE_SYSTEM)
#define SYS_STORE_I32(p, x) __hip_atomic_store((int*)(p), (x), \
    __ATOMIC_RELAXED, __HIP_MEMORY_SCOPE_SYSTEM)

#define MFMA(a, b, c) __builtin_amdgcn_mfma_f32_16x16x32_f16((a), (b), (c), 0, 0, 0)

// ---- sc0 (XCD-L2) ops: L1-bypass, L2-served, no cache maintenance ----------
__device__ __forceinline__ void l2_load_u64(unsigned long long& d, const void* p) {
  asm volatile("global_load_dwordx2 %0, %1, off sc0" : "=v"(d) : "v"(p) : "memory");
}
__device__ __forceinline__ void l2_store_u64(void* p, unsigned long long v) {
  asm volatile("global_store_dwordx2 %0, %1, off sc0" :: "v"(p), "v"(v) : "memory");
}
__device__ __forceinline__ int l2_load_flag(const void* p) {
  int v;
  asm volatile("global_load_dword %0, %1, off sc0\n\ts_waitcnt vmcnt(0)"
               : "=v"(v) : "v"(p) : "memory");
  return v;
}
__device__ __forceinline__ void l2_store_flag(void* p, int v) {
  asm volatile("global_store_dword %0, %1, off sc0" :: "v"(p), "v"(v) : "memory");
}
__device__ __forceinline__ void waitcnt0() {
  asm volatile("s_waitcnt vmcnt(0)" ::: "memory");
}
#define TIE16(b) asm volatile("s_waitcnt vmcnt(0)" \
  : "+v"(b[0]), "+v"(b[1]), "+v"(b[2]), "+v"(b[3]), "+v"(b[4]), "+v"(b[5]), \
    "+v"(b[6]), "+v"(b[7]), "+v"(b[8]), "+v"(b[9]), "+v"(b[10]), "+v"(b[11]), \
    "+v"(b[12]), "+v"(b[13]), "+v"(b[14]), "+v"(b[15]) :: "memory")

// ---------------- small prep kernels ----------------------------------------
__global__ __launch_bounds__(256) void cvt_kernel(const float* __restrict__ in,
                                                  f16* __restrict__ out, int n4) {
  int stride = gridDim.x * blockDim.x;
  for (int i = blockIdx.x * blockDim.x + threadIdx.x; i < n4; i += stride) {
    float4 v = reinterpret_cast<const float4*>(in)[i];
    _Float16 __attribute__((ext_vector_type(4))) h = { (f16)v.x, (f16)v.y,
                                                       (f16)v.z, (f16)v.w };
    reinterpret_cast<decltype(h)*>(out)[i] = h;
  }
}

__global__ __launch_bounds__(256) void bsum_kernel(const float* __restrict__ a,
                                                   const float* __restrict__ b,
                                                   float* __restrict__ o) {
  int i = blockIdx.x * blockDim.x + threadIdx.x;
  if (i < HH) o[i] = a[i] + b[i];
}

__global__ __launch_bounds__(256) void zero_kernel(int* __restrict__ p, int n) {
  int i = blockIdx.x * blockDim.x + threadIdx.x;
  if (i < n) p[i] = 0;
}

__global__ __launch_bounds__(256) void initout_kernel(float* __restrict__ out,
                                                      const float* __restrict__ fcb,
                                                      int n) {
  int i = blockIdx.x * blockDim.x + threadIdx.x;
  if (i < n) out[i] = fcb[0];
}

// ---------------- layer-pipelined persistent kernel --------------------------
__global__ __launch_bounds__(256, 1) void rnn_persist(
    const float* __restrict__ x,
    f16* __restrict__ ring0, f16* __restrict__ ring1, f16* __restrict__ ring2,
    f16* __restrict__ hfastg,
    const f16* __restrict__ wih0, const f16* __restrict__ wih1,
    const f16* __restrict__ wih2, const f16* __restrict__ wih3,
    const f16* __restrict__ whh0, const f16* __restrict__ whh1,
    const f16* __restrict__ whh2, const f16* __restrict__ whh3,
    const float* __restrict__ bs0, const float* __restrict__ bs1,
    const float* __restrict__ bs2, const float* __restrict__ bs3,
    const float* __restrict__ fcw, float* __restrict__ out,
    int* __restrict__ flag_fast, int* __restrict__ flag_sys,
    int* __restrict__ census) {
  const int p = blockIdx.x & 15, wgp = blockIdx.x >> 4;
  const int l = p >> 2, bg = p & 3;
  const int wave = threadIdx.x >> 6, lane = threadIdx.x & 63;
  const int l15 = lane & 15, quad = lane >> 4;
  const int b0 = bg * 16, r0 = wgp * 64;
  const int srow = threadIdx.x >> 4;        // batch row for h store
  const int scol = (threadIdx.x & 15) * 4;  // feature col group

  __shared__ f32x4 red[16 * 64];                 // 16 KB
  __shared__ __align__(16) f16 hstage[16 * 64];  // 2 KB
  __shared__ int sfast;

  // ---- XCD census: fast path iff all 16 wgs of this pair share an XCD ----
  {
    int xcc;
    asm volatile("s_getreg_b32 %0, hwreg(HW_REG_XCC_ID)" : "=s"(xcc));
    if (threadIdx.x == 0) SYS_STORE_I32(&census[p * 16 + wgp], xcc + 1);
    if (wave == 0) {
      int v = 1;
      for (;;) {
        v = (lane < 16) ? SYS_LOAD_I32(&census[p * 16 + lane]) : 1;
        if (__all(v != 0)) break;
      }
      int v0 = __shfl(v, 0, 64);
      int eq = __all((lane < 16) ? (v == v0) : 1);
      if (lane == 0) sfast = eq;
    }
    __syncthreads();
  }
  const bool fast = (sfast != 0);

  f16* rings[4] = { ring0, ring1, ring2, (f16*)0 };
  const f16* wih_t[4] = { wih0, wih1, wih2, wih3 };
  const f16* whh_t[4] = { whh0, whh1, whh2, whh3 };
  const float* bs_t[4] = { bs0, bs1, bs2, bs3 };

  const f16* in_ring = (l > 0) ? rings[l - 1] : (const f16*)0;
  f16* out_ring = rings[l];                 // null for l==3
  // ROUND-10 FIX: per-PAIR hfast (was per-bg: 4 layers aliased one buffer!)
  f16* hfast = hfastg + (size_t)p * 2 * 16 * HH;
  const float bv = bs_t[l][r0 + wave * 16 + l15];

  // ---- register-resident weight fragments ----
  f16x8 whhF[4][8];
  {
    const f16* q = whh_t[l] + (size_t)(r0 + l15) * HH + wave * 256 + quad * 8;
#pragma unroll
    for (int j = 0; j < 4; ++j)
#pragma unroll
      for (int f = 0; f < 8; ++f)
        whhF[j][f] = *reinterpret_cast<const f16x8*>(q + (size_t)j * 16 * HH + f * 32);
  }
  f16x8 wihF[4][8];
  if (l == 0) {
    const f16* q = wih0 + (size_t)(r0 + l15) * II + wave * 64 + quad * 8;
#pragma unroll
    for (int j = 0; j < 4; ++j)
#pragma unroll
      for (int f = 0; f < 2; ++f)
        wihF[j][f] = *reinterpret_cast<const f16x8*>(q + (size_t)j * 16 * II + f * 32);
  } else {
    const f16* q = wih_t[l] + (size_t)(r0 + l15) * HH + wave * 256 + quad * 8;
#pragma unroll
    for (int j = 0; j < 4; ++j)
#pragma unroll
      for (int f = 0; f < 8; ++f)
        wihF[j][f] = *reinterpret_cast<const f16x8*>(q + (size_t)j * 16 * HH + f * 32);
  }
  float4 fcwv = { 0.f, 0.f, 0.f, 0.f };
  if (l == 3) fcwv = *reinterpret_cast<const float4*>(fcw + r0 + (threadIdx.x & 15) * 4);

  // ---- poll config (wave 0): which=0 own(fast), 1 producer(sys), 2 consumer(sys)
  const int which = lane >> 4;
  int psel = p + (which == 1 ? -4 : which == 2 ? 4 : 0);
  psel = psel < 0 ? 0 : (psel > 15 ? 15 : psel);
  const int* fsysp = flag_sys + (psel * 16 + l15) * 16;
  const int* ffastp = flag_fast + (p * 16 + l15) * 16;
  unsigned long long needA = 0;
  if (l > 0) needA |= 0xFFFF0000ull;
  if (l < 3) needA |= 0xFFFF00000000ull;
  int* myff = flag_fast + (p * 16 + wgp) * 16;
  int* myfs = flag_sys + (p * 16 + wgp) * 16;
  const bool partA = (which == 1 && l > 0) || (which == 2 && l < 3);
  int pvA = 0;  // prefetched cross-pair flag (monotonic -> stale check safe)

  for (int t = 0; t < TT; ++t) {
    const int slot = t & (RING - 1);

    // ---- phase A: producer published in[t]; consumer freed ring slot ----
    if (wave == 0 && needA && (l > 0 || t + 1 >= RING)) {
      const int tgtA = (which == 1) ? t + 1 : t - RING + 1;
      int v = partA ? pvA : 0x7FFFFFFF;
      if ((__ballot(v >= tgtA) & needA) != needA) {
        for (;;) {
          v = partA ? SYS_LOAD_I32(fsysp) : 0x7FFFFFFF;
          if ((__ballot(v >= tgtA) & needA) == needA) break;
        }
      }
      pvA = partA ? SYS_LOAD_I32(fsysp) : 0x7FFFFFFF;  // async refresh
    }
    if (l > 0) __syncthreads();  // gate ih ring loads on phase A

    f32x4 c0 = {}, c1 = {}, c2 = {}, c3 = {};

    // ---- ih MFMAs (system ring loads; IC latency overlapped by MFMAs) ----
    if (l == 0) {
      const float* xp = x + ((size_t)(b0 + l15) * TT + t) * II + wave * 64 + quad * 8;
#pragma unroll
      for (int f = 0; f < 2; ++f) {
        float4 u0 = *reinterpret_cast<const float4*>(xp + f * 32);
        float4 u1 = *reinterpret_cast<const float4*>(xp + f * 32 + 4);
        f16x8 a = { (f16)u0.x, (f16)u0.y, (f16)u0.z, (f16)u0.w,
                    (f16)u1.x, (f16)u1.y, (f16)u1.z, (f16)u1.w };
        c0 = MFMA(a, wihF[0][f], c0);
        c1 = MFMA(a, wihF[1][f], c1);
        c2 = MFMA(a, wihF[2][f], c2);
        c3 = MFMA(a, wihF[3][f], c3);
      }
    } else {
      const char* ip = (const char*)(in_ring + ((size_t)(b0 + l15) * RING + slot) * HH +
                                     wave * 256 + quad * 8);
#pragma unroll
      for (int f = 0; f < 8; ++f) {
        U16u av;
        av.u[0] = SYS_LOAD_U64(ip + f * 64);
        av.u[1] = SYS_LOAD_U64(ip + f * 64 + 8);
        c0 = MFMA(av.v, wihF[0][f], c0);
        c1 = MFMA(av.v, wihF[1][f], c1);
        c2 = MFMA(av.v, wihF[2][f], c2);
        c3 = MFMA(av.v, wihF[3][f], c3);
      }
    }

    // ---- deferred system release for step t-1 (waitcnt covers own wave;
    //      barrier ensures ALL waves drained before tid0 publishes) ----
    if (t > 0) {
      waitcnt0();
      __syncthreads();
      if (threadIdx.x == 0) SYS_STORE_I32(myfs, t);
    }

    // ---- phase B: own pair finished step t-1 (fast: XCD-L2 sc0) ----
    if (t > 0) {
      if (wave == 0) {
        if (fast) {
          for (;;) {
            int v = (which == 0) ? l2_load_flag(ffastp) : 0x7FFFFFFF;
            if ((__ballot(v >= t) & 0xFFFFull) == 0xFFFFull) break;
          }
        } else {
          for (;;) {
            int v = (which == 0) ? SYS_LOAD_I32(ffastp) : 0x7FFFFFFF;
            if ((__ballot(v >= t) & 0xFFFFull) == 0xFFFFull) break;
          }
        }
      }
      __syncthreads();  // gate hfast loads on phase B

      // ---- hh loads from hfast ping-pong slot (t-1)&1 ----
      unsigned long long hbuf[16];
      const char* hp = (const char*)(hfast + (size_t)((t - 1) & 1) * 16 * HH +
                                     (size_t)l15 * HH + wave * 256 + quad * 8);
      if (fast) {
#pragma unroll
        for (int f = 0; f < 8; ++f) {
          l2_load_u64(hbuf[2 * f], hp + f * 64);
          l2_load_u64(hbuf[2 * f + 1], hp + f * 64 + 8);
        }
        TIE16(hbuf);
      } else {
#pragma unroll
        for (int f = 0; f < 8; ++f) {
          hbuf[2 * f] = SYS_LOAD_U64(hp + f * 64);
          hbuf[2 * f + 1] = SYS_LOAD_U64(hp + f * 64 + 8);
        }
      }
#pragma unroll
      for (int f = 0; f < 8; ++f) {
        U16u av;
        av.u[0] = hbuf[2 * f];
        av.u[1] = hbuf[2 * f + 1];
        c0 = MFMA(av.v, whhF[0][f], c0);
        c1 = MFMA(av.v, whhF[1][f], c1);
        c2 = MFMA(av.v, whhF[2][f], c2);
        c3 = MFMA(av.v, whhF[3][f], c3);
      }
    }

    // ---- cross-wave K-reduce: wave w takes n-tile w ----
    red[(wave * 4 + 0) * 64 + lane] = c0;
    red[(wave * 4 + 1) * 64 + lane] = c1;
    red[(wave * 4 + 2) * 64 + lane] = c2;
    red[(wave * 4 + 3) * 64 + lane] = c3;
    __syncthreads();
    f32x4 tot = red[(0 * 4 + wave) * 64 + lane] + red[(1 * 4 + wave) * 64 + lane] +
                red[(2 * 4 + wave) * 64 + lane] + red[(3 * 4 + wave) * 64 + lane];

    // ---- bias + tanh, repack to [batch][feature] ----
#pragma unroll
    for (int i = 0; i < 4; ++i) {
      float e = __expf(2.0f * (tot[i] + bv));   // tanh(x) = 1 - 2/(e^{2x}+1)
      hstage[(quad * 4 + i) * 64 + wave * 16 + l15] = (f16)(1.0f - 2.0f / (e + 1.0f));
    }
    __syncthreads();

    // ---- fast release: hfast sc0 store -> ack -> barrier -> flag_fast ----
    unsigned long long hw =
        *reinterpret_cast<const unsigned long long*>(&hstage[srow * 64 + scol]);
    {
      void* dst = hfast + (size_t)(t & 1) * 16 * HH + (size_t)srow * HH + r0 + scol;
      if (fast) l2_store_u64(dst, hw);
      else      SYS_STORE_U64(dst, hw);
    }
    waitcnt0();       // own wave's hfast stores acked (L2 / IC)
    __syncthreads();  // all waves drained
    if (threadIdx.x == 0) {
      if (fast) l2_store_flag(myff, t + 1);
      else      SYS_STORE_I32(myff, t + 1);
    }

    // ---- off-critical-path: ring stores (system) / fused FC; drained at
    //      next step's deferred release ----
    if (l < 3) {
      SYS_STORE_U64(out_ring + ((size_t)(b0 + srow) * RING + slot) * HH + r0 + scol, hw);
    } else {
      union { unsigned long long u; f16 h[4]; } hu;
      hu.u = hw;
      float partial = (float)hu.h[0] * fcwv.x + (float)hu.h[1] * fcwv.y +
                      (float)hu.h[2] * fcwv.z + (float)hu.h[3] * fcwv.w;
      partial += __shfl_down(partial, 8, 16);
      partial += __shfl_down(partial, 4, 16);
      partial += __shfl_down(partial, 2, 16);
      partial += __shfl_down(partial, 1, 16);
      if ((threadIdx.x & 15) == 0)
        atomicAdd(out + (size_t)(b0 + srow) * TT + t, partial);
    }
  }

  // ---- epilogue: publish final flag_sys (fixed protocol) ----
  waitcnt0();
  __syncthreads();
  if (threadIdx.x == 0) SYS_STORE_I32(myfs, TT);
}

extern "C" void kernel_launch(void* const* d_in, const int* in_sizes, int n_in,
                              void* d_out, int out_size, void* d_ws, size_t ws_size,
                              hipStream_t stream) {
  const float* x   = (const float*)d_in[0];
  const float* fcw = (const float*)d_in[17];
  const float* fcb = (const float*)d_in[18];

  char* ws = (char*)d_ws;
  size_t off = 0;
  auto alloc = [&](size_t bytes) -> void* {
    void* p = ws + off;
    off += (bytes + 255) & ~(size_t)255;
    return p;
  };
  f16* ring[3];
  for (int l = 0; l < 3; ++l)
    ring[l] = (f16*)alloc((size_t)BB * RING * HH * 2);        // 8 MB each
  f16* hfast = (f16*)alloc((size_t)16 * 2 * 16 * HH * 2);     // 1 MB (per-PAIR)
  f16* w16ih[4];
  f16* w16hh[4];
  float* bsum[4];
  for (int l = 0; l < 4; ++l) {
    int din = (l == 0) ? II : HH;
    w16ih[l] = (f16*)alloc((size_t)HH * din * 2);
    w16hh[l] = (f16*)alloc((size_t)HH * HH * 2);
    bsum[l]  = (float*)alloc(HH * 4);
  }
  int* flag_fast = (int*)alloc(256 * 16 * 4);  // 64B-spread
  int* flag_sys  = (int*)alloc(256 * 16 * 4);
  int* census    = (int*)alloc(256 * 4);       // total ~40 MB

  for (int l = 0; l < 4; ++l) {
    int din = (l == 0) ? II : HH;
    cvt_kernel<<<512, 256, 0, stream>>>((const float*)d_in[1 + 4 * l], w16ih[l],
                                        HH * din / 4);
    cvt_kernel<<<512, 256, 0, stream>>>((const float*)d_in[2 + 4 * l], w16hh[l],
                                        HH * HH / 4);
    bsum_kernel<<<4, 256, 0, stream>>>((const float*)d_in[3 + 4 * l],
                                       (const float*)d_in[4 + 4 * l], bsum[l]);
  }
  zero_kernel<<<17, 256, 0, stream>>>(flag_fast, 256 * 16);
  zero_kernel<<<17, 256, 0, stream>>>(flag_sys, 256 * 16);
  zero_kernel<<<1, 256, 0, stream>>>(census, 256);
  initout_kernel<<<BB * TT / 256, 256, 0, stream>>>((float*)d_out, fcb, BB * TT);

  rnn_persist<<<256, 256, 0, stream>>>(
      x, ring[0], ring[1], ring[2], hfast,
      w16ih[0], w16ih[1], w16ih[2], w16ih[3],
      w16hh[0], w16hh[1], w16hh[2], w16hh[3],
      bsum[0], bsum[1], bsum[2], bsum[3],
      fcw, (float*)d_out, flag_fast, flag_sys, census);
}